// Round 1
// baseline (17489.708 us; speedup 1.0000x reference)
//
#include <hip/hip_runtime.h>

#define NPLANES 24
#define IMG_W 192
#define TSTEPS 926   // wavefront t = 0..925, t = 4*i + j
#define MAXC 47      // max cells per wavefront step

__device__ __forceinline__ float fast_tanh(float x) {
  float e = __expf(2.0f * x);
  return 1.0f - 2.0f / (e + 1.0f);
}

// One block per (b,c) plane. 512 threads = 8 waves.
// lane = cell within wavefront; waves split the neurons of each layer.
// Weight reads are wave-uniform -> scalar s_load pipe (free of VALU/LDS cost).
__launch_bounds__(512)
__global__ void codec_kernel(const float* __restrict__ x,
                             const float* __restrict__ W1g, const float* __restrict__ b1g,
                             const float* __restrict__ W2g, const float* __restrict__ b2g,
                             const float* __restrict__ W3g, const float* __restrict__ b3g,
                             const float* __restrict__ W4g, const float* __restrict__ b4g,
                             float* __restrict__ ws)
{
  // delta ring: 64 full-width rows (reuse distance 64 > live span ~50).
  // row slot (i & 63); col 3+j holds delta(i,j); cols 0..2 / 189..191 stay 0 (padding).
  __shared__ float ringL[64 * IMG_W];   // 49152 B
  __shared__ float featL[MAXC * 52];    //  9776 B (48 feats, stride 52 for banks)
  __shared__ float h1L[MAXC * 100];     // 18800 B (96, stride 100)
  __shared__ float h2L[MAXC * 28];      //  5264 B (24, stride 28)
  __shared__ float h3L[MAXC * 12];      //  2256 B
  // total ~85 KB < 160 KB gfx950 group segment

  const int tid  = threadIdx.x;
  const int lane = tid & 63;
  // readfirstlane: force wave-uniformity so weight loads go down the scalar pipe
  const int w = __builtin_amdgcn_readfirstlane(tid >> 6);   // wave id 0..7
  const int plane = blockIdx.x;
  const float* __restrict__ xp = x + (size_t)plane * (IMG_W * IMG_W);

  for (int u = tid; u < 64 * IMG_W; u += 512) ringL[u] = 0.0f;
  __syncthreads();

  float sumsq = 0.0f;

  for (int t = 0; t < TSTEPS; ++t) {
    int i_min = (t <= 185) ? 0 : ((t - 182) >> 2);  // ceil((t-185)/4)
    int i_max = t >> 2; if (i_max > 185) i_max = 185;
    const int ncells = i_max - i_min + 1;

    // ---- gather 48 features per cell into featL ----
    {
      const int tot = ncells * 48;
      for (int u = tid; u < tot; u += 512) {
        int c = u / 48;
        int f = u - c * 48;
        int i = i_min + c;
        int j = t - 4 * i;
        float v;
        if (f < 21) {                 // 3 rows above, 7 cols each (x)
          v = xp[(i + f / 7) * IMG_W + (j + f % 7)];
        } else if (f < 24) {          // same row, 3 cols left (x)
          v = xp[(i + 3) * IMG_W + (j + (f - 21))];
        } else if (f < 45) {          // 21 delta taps from rows i-3..i-1
          int p = f - 24;
          v = ringL[(((i - 3 + p / 7) & 63) * IMG_W) + (j + p % 7)];
        } else {                      // last3: deltas (i, j-3..j-1)
          v = ringL[((i & 63) * IMG_W) + (j + (f - 45))];
        }
        featL[c * 52 + f] = v;
      }
    }
    __syncthreads();

    // ---- layer 1: 48 -> 96, wave w handles neurons 12w..12w+11 ----
    {
      int c = lane;
      if (c < ncells) {
        float fr[48];
        #pragma unroll
        for (int q = 0; q < 12; ++q)
          *(float4*)&fr[4*q] = *(const float4*)&featL[c * 52 + 4*q];
        float acc[12];
        #pragma unroll
        for (int m = 0; m < 12; ++m) acc[m] = b1g[w * 12 + m];
        #pragma unroll
        for (int k = 0; k < 48; ++k) {
          float fk = fr[k];
          #pragma unroll
          for (int m = 0; m < 12; ++m)
            acc[m] = fmaf(fk, W1g[k * 96 + w * 12 + m], acc[m]);  // contiguous s_loads
        }
        #pragma unroll
        for (int m = 0; m < 12; ++m)
          h1L[c * 100 + w * 12 + m] = fast_tanh(acc[m]);
      }
    }
    __syncthreads();

    // ---- layer 2: 96 -> 24, waves 0..3, 6 neurons each ----
    if (w < 4) {
      int c = lane;
      if (c < ncells) {
        float hr[96];
        #pragma unroll
        for (int q = 0; q < 24; ++q)
          *(float4*)&hr[4*q] = *(const float4*)&h1L[c * 100 + 4*q];
        float acc[6];
        #pragma unroll
        for (int m = 0; m < 6; ++m) acc[m] = b2g[w * 6 + m];
        #pragma unroll
        for (int k = 0; k < 96; ++k) {
          float hk = hr[k];
          #pragma unroll
          for (int m = 0; m < 6; ++m)
            acc[m] = fmaf(hk, W2g[k * 24 + w * 6 + m], acc[m]);
        }
        #pragma unroll
        for (int m = 0; m < 6; ++m)
          h2L[c * 28 + w * 6 + m] = fast_tanh(acc[m]);
      }
    }
    __syncthreads();

    // ---- layer 3: 24 -> 12, waves 0..3, 3 neurons each ----
    if (w < 4) {
      int c = lane;
      if (c < ncells) {
        float hr[24];
        #pragma unroll
        for (int q = 0; q < 6; ++q)
          *(float4*)&hr[4*q] = *(const float4*)&h2L[c * 28 + 4*q];
        float acc[3];
        #pragma unroll
        for (int m = 0; m < 3; ++m) acc[m] = b3g[w * 3 + m];
        #pragma unroll
        for (int k = 0; k < 24; ++k) {
          float hk = hr[k];
          #pragma unroll
          for (int m = 0; m < 3; ++m)
            acc[m] = fmaf(hk, W3g[k * 12 + w * 3 + m], acc[m]);
        }
        #pragma unroll
        for (int m = 0; m < 3; ++m)
          h3L[c * 12 + w * 3 + m] = fast_tanh(acc[m]);
      }
    }
    __syncthreads();

    // ---- layer 4 (12 -> 1) + delta + ring write, wave 0 only ----
    if (w == 0) {
      int c = lane;
      if (c < ncells) {
        float hr[12];
        #pragma unroll
        for (int q = 0; q < 3; ++q)
          *(float4*)&hr[4*q] = *(const float4*)&h3L[c * 12 + 4*q];
        float acc = b4g[0];
        #pragma unroll
        for (int k = 0; k < 12; ++k)
          acc = fmaf(hr[k], W4g[k], acc);
        float pred = fast_tanh(acc);
        int i = i_min + c;
        int j = t - 4 * i;
        float tgt = xp[(i + 3) * IMG_W + (j + 3)];
        float d = tgt - pred;
        ringL[(i & 63) * IMG_W + (j + 3)] = d;
        sumsq += d * d;
      }
    }
    __syncthreads();  // ring writes visible before next step's gather
  }

  // only wave 0 holds nonzero partials
  if (w == 0) {
    #pragma unroll
    for (int off = 32; off >= 1; off >>= 1)
      sumsq += __shfl_down(sumsq, off);
    if (lane == 0) ws[plane] = sumsq;
  }
}

__global__ void finalize_kernel(const float* __restrict__ ws, float* __restrict__ out) {
  if (threadIdx.x == 0) {
    float s = 0.0f;
    #pragma unroll
    for (int p = 0; p < NPLANES; ++p) s += ws[p];
    // divisor: b*c*(h-2)*w = 8*3*190*192
    out[0] = sqrtf(s / 875520.0f);
  }
}

extern "C" void kernel_launch(void* const* d_in, const int* in_sizes, int n_in,
                              void* d_out, int out_size, void* d_ws, size_t ws_size,
                              hipStream_t stream) {
  (void)in_sizes; (void)n_in; (void)out_size; (void)ws_size;
  const float* x  = (const float*)d_in[0];
  const float* W1 = (const float*)d_in[1];
  const float* b1 = (const float*)d_in[2];
  const float* W2 = (const float*)d_in[3];
  const float* b2 = (const float*)d_in[4];
  const float* W3 = (const float*)d_in[5];
  const float* b3 = (const float*)d_in[6];
  const float* W4 = (const float*)d_in[7];
  const float* b4 = (const float*)d_in[8];
  float* ws = (float*)d_ws;   // 24 per-plane partial sums (overwritten every call)

  codec_kernel<<<NPLANES, 512, 0, stream>>>(x, W1, b1, W2, b2, W3, b3, W4, b4, ws);
  finalize_kernel<<<1, 64, 0, stream>>>(ws, (float*)d_out);
}

// Round 2
// 6629.073 us; speedup vs baseline: 2.6383x; 2.6383x over previous
//
#include <hip/hip_runtime.h>

#define NPLANES 24
#define IMG_W 192
#define TSTEPS 926   // wavefront t = 0..925, t = 4*i + j
#define MAXC 47      // max cells per wavefront step

__device__ __forceinline__ float fast_tanh(float x) {
  float e = __expf(2.0f * x);
  return 1.0f - 2.0f / (e + 1.0f);
}

// One block per (b,c) plane. 512 threads = 8 waves.
// lane = cell within wavefront step; waves split the neurons of each layer.
// All weights live in LDS (transposed neuron-major): weight reads are
// wave-uniform ds_read_b128 broadcasts (16B-aligned rows), read exactly once
// per step across the block. No per-step global/scalar weight traffic.
__launch_bounds__(512)
__global__ void codec_kernel(const float* __restrict__ x,
                             const float* __restrict__ W1g, const float* __restrict__ b1g,
                             const float* __restrict__ W2g, const float* __restrict__ b2g,
                             const float* __restrict__ W3g, const float* __restrict__ b3g,
                             const float* __restrict__ W4g, const float* __restrict__ b4g,
                             float* __restrict__ ws)
{
  // delta ring: 64 full-width rows (reuse distance 64 > live span ~50).
  // row slot (i & 63); col 3+j holds delta(i,j); cols 0..2 / 189..191 stay 0.
  __shared__ float ringL[64 * IMG_W];    // 49152 B
  __shared__ float featL[MAXC * 52];     //  9776 B (48 feats, stride 52)
  __shared__ float h1L[MAXC * 100];      // 18800 B (96, stride 100)
  __shared__ float h2L[MAXC * 28];       //  5264 B (24, stride 28)
  __shared__ float h3L[MAXC * 12];       //  2256 B
  // weights, neuron-major (k contiguous): every row is a multiple of 16B
  __shared__ float w1T[96 * 48];         // 18432 B
  __shared__ float w2T[24 * 96];         //  9216 B
  __shared__ float w3T[12 * 24];         //  1152 B
  __shared__ float w4L[12];
  __shared__ float b1L[96], b2L[24], b3L[12], b4L[1];
  // total ~113 KB < 160 KB group segment

  const int tid  = threadIdx.x;
  const int lane = tid & 63;
  const int w = __builtin_amdgcn_readfirstlane(tid >> 6);   // wave id 0..7
  const int plane = blockIdx.x;
  const float* __restrict__ xp = x + (size_t)plane * (IMG_W * IMG_W);

  // ---- one-time init: zero ring, stage weights (transposed) ----
  for (int u = tid; u < 64 * IMG_W; u += 512) ringL[u] = 0.0f;
  for (int u = tid; u < 96 * 48; u += 512) { int n = u / 48; int k = u - n * 48; w1T[u] = W1g[k * 96 + n]; }
  for (int u = tid; u < 24 * 96; u += 512) { int n = u / 96; int k = u - n * 96; w2T[u] = W2g[k * 24 + n]; }
  for (int u = tid; u < 12 * 24; u += 512) { int n = u / 24; int k = u - n * 24; w3T[u] = W3g[k * 12 + n]; }
  if (tid < 12) w4L[tid] = W4g[tid];
  if (tid < 96) b1L[tid] = b1g[tid];
  if (tid < 24) b2L[tid] = b2g[tid];
  if (tid < 12) b3L[tid] = b3g[tid];
  if (tid == 0) b4L[0] = b4g[0];
  __syncthreads();

  float sumsq = 0.0f;

  for (int t = 0; t < TSTEPS; ++t) {
    int i_min = (t <= 185) ? 0 : ((t - 182) >> 2);
    int i_max = t >> 2; if (i_max > 185) i_max = 185;
    const int ncells = i_max - i_min + 1;

    // ---- gather 48 features per cell into featL ----
    {
      const int tot = ncells * 48;
      for (int u = tid; u < tot; u += 512) {
        int c = u / 48;
        int f = u - c * 48;
        int i = i_min + c;
        int j = t - 4 * i;
        float v;
        if (f < 21) {                 // 3 rows above, 7 cols each (x)
          v = xp[(i + f / 7) * IMG_W + (j + f % 7)];
        } else if (f < 24) {          // same row, 3 cols left (x)
          v = xp[(i + 3) * IMG_W + (j + (f - 21))];
        } else if (f < 45) {          // 21 delta taps from rows i-3..i-1
          int p = f - 24;
          v = ringL[(((i - 3 + p / 7) & 63) * IMG_W) + (j + p % 7)];
        } else {                      // last3: deltas (i, j-3..j-1)
          v = ringL[((i & 63) * IMG_W) + (j + (f - 45))];
        }
        featL[c * 52 + f] = v;
      }
    }
    __syncthreads();

    // ---- layer 1: 48 -> 96, wave w -> neurons 12w..12w+11 ----
    {
      int c = lane;
      if (c < ncells) {
        float fr[48];
        #pragma unroll
        for (int q = 0; q < 12; ++q)
          *(float4*)&fr[4*q] = *(const float4*)&featL[c * 52 + 4*q];  // c*208B, 16B-aligned
        #pragma unroll
        for (int m = 0; m < 12; ++m) {
          const int n = w * 12 + m;
          const float* __restrict__ wr = &w1T[n * 48];
          float a = b1L[n];
          #pragma unroll
          for (int q = 0; q < 12; ++q) {
            float4 wv = *(const float4*)&wr[4*q];  // wave-uniform broadcast
            a = fmaf(fr[4*q+0], wv.x, a);
            a = fmaf(fr[4*q+1], wv.y, a);
            a = fmaf(fr[4*q+2], wv.z, a);
            a = fmaf(fr[4*q+3], wv.w, a);
          }
          h1L[c * 100 + n] = fast_tanh(a);
        }
      }
    }
    __syncthreads();

    // ---- layer 2: 96 -> 24, wave w -> neurons 3w..3w+2 ----
    {
      int c = lane;
      if (c < ncells) {
        float hr[96];
        #pragma unroll
        for (int q = 0; q < 24; ++q)
          *(float4*)&hr[4*q] = *(const float4*)&h1L[c * 100 + 4*q];  // c*400B aligned
        #pragma unroll
        for (int m = 0; m < 3; ++m) {
          const int n = w * 3 + m;
          const float* __restrict__ wr = &w2T[n * 96];
          float a = b2L[n];
          #pragma unroll
          for (int q = 0; q < 24; ++q) {
            float4 wv = *(const float4*)&wr[4*q];
            a = fmaf(hr[4*q+0], wv.x, a);
            a = fmaf(hr[4*q+1], wv.y, a);
            a = fmaf(hr[4*q+2], wv.z, a);
            a = fmaf(hr[4*q+3], wv.w, a);
          }
          h2L[c * 28 + n] = fast_tanh(a);
        }
      }
    }
    __syncthreads();

    // ---- layer 3: 24 -> 12, waves 0..5 -> 2 neurons each ----
    if (w < 6) {
      int c = lane;
      if (c < ncells) {
        float hr[24];
        #pragma unroll
        for (int q = 0; q < 6; ++q)
          *(float4*)&hr[4*q] = *(const float4*)&h2L[c * 28 + 4*q];  // c*112B aligned
        #pragma unroll
        for (int m = 0; m < 2; ++m) {
          const int n = w * 2 + m;
          const float* __restrict__ wr = &w3T[n * 24];
          float a = b3L[n];
          #pragma unroll
          for (int q = 0; q < 6; ++q) {
            float4 wv = *(const float4*)&wr[4*q];
            a = fmaf(hr[4*q+0], wv.x, a);
            a = fmaf(hr[4*q+1], wv.y, a);
            a = fmaf(hr[4*q+2], wv.z, a);
            a = fmaf(hr[4*q+3], wv.w, a);
          }
          h3L[c * 12 + n] = fast_tanh(a);
        }
      }
    }
    __syncthreads();

    // ---- layer 4 (12 -> 1) + delta + ring write, wave 0 only ----
    if (w == 0) {
      int c = lane;
      if (c < ncells) {
        float hr[12];
        #pragma unroll
        for (int q = 0; q < 3; ++q)
          *(float4*)&hr[4*q] = *(const float4*)&h3L[c * 12 + 4*q];  // c*48B aligned
        float a = b4L[0];
        #pragma unroll
        for (int q = 0; q < 3; ++q) {
          float4 wv = *(const float4*)&w4L[4*q];
          a = fmaf(hr[4*q+0], wv.x, a);
          a = fmaf(hr[4*q+1], wv.y, a);
          a = fmaf(hr[4*q+2], wv.z, a);
          a = fmaf(hr[4*q+3], wv.w, a);
        }
        float pred = fast_tanh(a);
        int i = i_min + c;
        int j = t - 4 * i;
        float tgt = xp[(i + 3) * IMG_W + (j + 3)];
        float d = tgt - pred;
        ringL[(i & 63) * IMG_W + (j + 3)] = d;
        sumsq += d * d;
      }
    }
    __syncthreads();  // ring writes visible before next step's gather
  }

  if (w == 0) {
    #pragma unroll
    for (int off = 32; off >= 1; off >>= 1)
      sumsq += __shfl_down(sumsq, off);
    if (lane == 0) ws[plane] = sumsq;
  }
}

__global__ void finalize_kernel(const float* __restrict__ ws, float* __restrict__ out) {
  if (threadIdx.x == 0) {
    float s = 0.0f;
    #pragma unroll
    for (int p = 0; p < NPLANES; ++p) s += ws[p];
    // divisor: b*c*(h-2)*w = 8*3*190*192
    out[0] = sqrtf(s / 875520.0f);
  }
}

extern "C" void kernel_launch(void* const* d_in, const int* in_sizes, int n_in,
                              void* d_out, int out_size, void* d_ws, size_t ws_size,
                              hipStream_t stream) {
  (void)in_sizes; (void)n_in; (void)out_size; (void)ws_size;
  const float* x  = (const float*)d_in[0];
  const float* W1 = (const float*)d_in[1];
  const float* b1 = (const float*)d_in[2];
  const float* W2 = (const float*)d_in[3];
  const float* b2 = (const float*)d_in[4];
  const float* W3 = (const float*)d_in[5];
  const float* b3 = (const float*)d_in[6];
  const float* W4 = (const float*)d_in[7];
  const float* b4 = (const float*)d_in[8];
  float* ws = (float*)d_ws;

  codec_kernel<<<NPLANES, 512, 0, stream>>>(x, W1, b1, W2, b2, W3, b3, W4, b4, ws);
  finalize_kernel<<<1, 64, 0, stream>>>(ws, (float*)d_out);
}

// Round 3
// 5720.338 us; speedup vs baseline: 3.0575x; 1.1589x over previous
//
#include <hip/hip_runtime.h>

#define NPLANES 24
#define IMG 192
#define RING_W 193   // 64-row delta ring, stride 193 (odd mod 32 -> conflict-free lane access)
#define TSTEPS 926   // wavefront t = 4*i + j, t = 0..925

__device__ __forceinline__ float fast_tanh(float x) {
  float e = __expf(2.0f * x);
  return 1.0f - 2.0f / (e + 1.0f);
}

// One block per (b,c) plane, 512 threads = 8 waves.
// Fixed lane<->row binding: lane L handles interior row i == L (mod 64); at any
// step the active row window is < 64 wide so the mapping is unique. Each lane
// keeps its 24-tap x-window in REGISTERS (slides right 1 col/step, 4 global
// loads), reads its 24 delta taps per-lane from the LDS ring. No gather phase.
// Waves split neurons: A: L1 (12 n/wave), B: L2 (3 n/wave),
// C: L3 2n + L4-partial (waves 0-5), D: L4 finish + ring write (wave 0).
__launch_bounds__(512)
__global__ void codec_kernel(const float* __restrict__ x,
                             const float* __restrict__ W1g, const float* __restrict__ b1g,
                             const float* __restrict__ W2g, const float* __restrict__ b2g,
                             const float* __restrict__ W3g, const float* __restrict__ b3g,
                             const float* __restrict__ W4g, const float* __restrict__ b4g,
                             float* __restrict__ ws)
{
  __shared__ float ringL[64 * RING_W];  // 49408 B; cols 0..2,189..191 stay 0 (padding)
  __shared__ float h1L[64 * 100];       // 25600 B (96 vals, stride 100)
  __shared__ float h2L[64 * 28];        //  7168 B (24 vals, stride 28)
  __shared__ float p4L[64 * 9];         //  2304 B (6 partials, stride 9)
  __shared__ float w1T[96 * 48];        // 18432 B neuron-major
  __shared__ float w2T[24 * 96];        //  9216 B
  __shared__ float w3T[12 * 24];        //  1152 B
  __shared__ float w4L[12];
  __shared__ float b1L[96], b2L[24], b3L[12], b4L[1];
  // total ~114 KB < 160 KB

  const int tid  = threadIdx.x;
  const int lane = tid & 63;
  const int w = __builtin_amdgcn_readfirstlane(tid >> 6);   // wave id 0..7
  const float* __restrict__ xp = x + (size_t)blockIdx.x * (IMG * IMG);

  for (int u = tid; u < 64 * RING_W; u += 512) ringL[u] = 0.0f;
  for (int u = tid; u < 96 * 48; u += 512) { int n = u / 48, k = u - n * 48; w1T[u] = W1g[k * 96 + n]; }
  for (int u = tid; u < 24 * 96; u += 512) { int n = u / 96, k = u - n * 96; w2T[u] = W2g[k * 24 + n]; }
  for (int u = tid; u < 12 * 24; u += 512) { int n = u / 24, k = u - n * 24; w3T[u] = W3g[k * 12 + n]; }
  if (tid < 12) w4L[tid] = W4g[tid];
  if (tid < 96) b1L[tid] = b1g[tid];
  if (tid < 24) b2L[tid] = b2g[tid];
  if (tid < 12) b3L[tid] = b3g[tid];
  if (tid == 0) b4L[0] = b4g[0];
  __syncthreads();

  // per-lane sliding x-window (full-image coords: rows i..i+2 cols j..j+6,
  // row i+3 cols j..j+2, target x[i+3][j+3]) — maintained redundantly per wave
  float xw[3][7], xl[3], xt = 0.0f;
  float sumsq = 0.0f;

  for (int t = 0; t < TSTEPS; ++t) {
    const int i_min = (t <= 185) ? 0 : ((t - 182) >> 2);
    const int i_max = (t >> 2) > 185 ? 185 : (t >> 2);
    const int k64 = (i_min - lane + 63) >> 6;
    const int i = lane + (k64 << 6);          // unique row ≡ lane (mod 64) in window
    const bool active = (i <= i_max);
    const int j = t - 4 * i;                  // valid only when active
    float fr[48];

    // ---- phase A: window update + ring taps + L1 (12 neurons / wave) ----
    if (active) {
      const float* xrow = xp + i * IMG + j;
      if (j == 0) {                           // row start: cold-load window
        #pragma unroll
        for (int r = 0; r < 3; ++r)
          #pragma unroll
          for (int c = 0; c < 7; ++c) xw[r][c] = xrow[r * IMG + c];
        #pragma unroll
        for (int c = 0; c < 3; ++c) xl[c] = xrow[3 * IMG + c];
        xt = xrow[3 * IMG + 3];
      } else {                                // slide right by one column
        #pragma unroll
        for (int r = 0; r < 3; ++r) {
          #pragma unroll
          for (int c = 0; c < 6; ++c) xw[r][c] = xw[r][c + 1];
          xw[r][6] = xrow[r * IMG + 6];
        }
        xl[0] = xl[1]; xl[1] = xl[2]; xl[2] = xt;
        xt = xrow[3 * IMG + 3];
      }
      // delta taps: rows i-3..i-1 cols j-3..j+3, row i cols j-3..j-1
      const int base0 = ((i - 3) & 63) * RING_W + j;
      const int base1 = ((i - 2) & 63) * RING_W + j;
      const int base2 = ((i - 1) & 63) * RING_W + j;
      const int base3 = (i & 63) * RING_W + j;
      #pragma unroll
      for (int d = 0; d < 7; ++d) fr[24 + d]      = ringL[base0 + d];
      #pragma unroll
      for (int d = 0; d < 7; ++d) fr[24 + 7 + d]  = ringL[base1 + d];
      #pragma unroll
      for (int d = 0; d < 7; ++d) fr[24 + 14 + d] = ringL[base2 + d];
      #pragma unroll
      for (int d = 0; d < 3; ++d) fr[45 + d]      = ringL[base3 + d];
      #pragma unroll
      for (int r = 0; r < 3; ++r)
        #pragma unroll
        for (int c = 0; c < 7; ++c) fr[7 * r + c] = xw[r][c];
      fr[21] = xl[0]; fr[22] = xl[1]; fr[23] = xl[2];

      #pragma unroll
      for (int mm = 0; mm < 3; ++mm) {        // 12 neurons as 3 float4 groups
        float o4[4];
        #pragma unroll
        for (int m4 = 0; m4 < 4; ++m4) {
          const int n = w * 12 + mm * 4 + m4;
          const float* wr = &w1T[n * 48];
          float a = b1L[n];
          #pragma unroll
          for (int q = 0; q < 12; ++q) {
            float4 wv = *(const float4*)&wr[4 * q];   // wave-uniform broadcast
            a = fmaf(fr[4*q+0], wv.x, a);
            a = fmaf(fr[4*q+1], wv.y, a);
            a = fmaf(fr[4*q+2], wv.z, a);
            a = fmaf(fr[4*q+3], wv.w, a);
          }
          o4[m4] = fast_tanh(a);
        }
        *(float4*)&h1L[lane * 100 + w * 12 + mm * 4] =
            make_float4(o4[0], o4[1], o4[2], o4[3]);  // 16B-aligned (w*48B)
      }
    }
    __syncthreads();

    // ---- phase B: L2, 3 neurons / wave, h1 streamed once ----
    if (active) {
      const int n0 = w * 3;
      const float* wr0 = &w2T[(n0 + 0) * 96];
      const float* wr1 = &w2T[(n0 + 1) * 96];
      const float* wr2 = &w2T[(n0 + 2) * 96];
      float a0 = b2L[n0], a1 = b2L[n0 + 1], a2 = b2L[n0 + 2];
      #pragma unroll
      for (int q = 0; q < 24; ++q) {
        float4 hq = *(const float4*)&h1L[lane * 100 + 4 * q];
        float4 u0 = *(const float4*)&wr0[4 * q];
        float4 u1 = *(const float4*)&wr1[4 * q];
        float4 u2 = *(const float4*)&wr2[4 * q];
        a0 = fmaf(hq.x, u0.x, a0); a0 = fmaf(hq.y, u0.y, a0);
        a0 = fmaf(hq.z, u0.z, a0); a0 = fmaf(hq.w, u0.w, a0);
        a1 = fmaf(hq.x, u1.x, a1); a1 = fmaf(hq.y, u1.y, a1);
        a1 = fmaf(hq.z, u1.z, a1); a1 = fmaf(hq.w, u1.w, a1);
        a2 = fmaf(hq.x, u2.x, a2); a2 = fmaf(hq.y, u2.y, a2);
        a2 = fmaf(hq.z, u2.z, a2); a2 = fmaf(hq.w, u2.w, a2);
      }
      h2L[lane * 28 + n0 + 0] = fast_tanh(a0);
      h2L[lane * 28 + n0 + 1] = fast_tanh(a1);
      h2L[lane * 28 + n0 + 2] = fast_tanh(a2);
    }
    __syncthreads();

    // ---- phase C: L3 (2 neurons) + L4 partial, waves 0..5 ----
    if (w < 6) {
      if (active) {
        float g[24];
        #pragma unroll
        for (int q = 0; q < 6; ++q)
          *(float4*)&g[4*q] = *(const float4*)&h2L[lane * 28 + 4 * q];
        float p = 0.0f;
        #pragma unroll
        for (int m = 0; m < 2; ++m) {
          const int n = w * 2 + m;
          const float* wr = &w3T[n * 24];
          float a = b3L[n];
          #pragma unroll
          for (int q = 0; q < 6; ++q) {
            float4 wv = *(const float4*)&wr[4 * q];
            a = fmaf(g[4*q+0], wv.x, a);
            a = fmaf(g[4*q+1], wv.y, a);
            a = fmaf(g[4*q+2], wv.z, a);
            a = fmaf(g[4*q+3], wv.w, a);
          }
          p = fmaf(fast_tanh(a), w4L[n], p);
        }
        p4L[lane * 9 + w] = p;
      }
    }
    __syncthreads();

    // ---- phase D: wave 0 sums partials, writes delta to ring ----
    if (w == 0) {
      if (active) {
        float s = b4L[0];
        #pragma unroll
        for (int q = 0; q < 6; ++q) s += p4L[lane * 9 + q];
        float pred = fast_tanh(s);
        float d = xt - pred;
        ringL[(i & 63) * RING_W + j + 3] = d;
        sumsq += d * d;
      }
    }
    __syncthreads();   // ring visible before next step's taps
  }

  if (w == 0) {
    #pragma unroll
    for (int off = 32; off >= 1; off >>= 1)
      sumsq += __shfl_down(sumsq, off);
    if (lane == 0) ws[blockIdx.x] = sumsq;
  }
}

__global__ void finalize_kernel(const float* __restrict__ ws, float* __restrict__ out) {
  if (threadIdx.x == 0) {
    float s = 0.0f;
    #pragma unroll
    for (int p = 0; p < NPLANES; ++p) s += ws[p];
    // divisor: b*c*(h-2)*w = 8*3*190*192
    out[0] = sqrtf(s / 875520.0f);
  }
}

extern "C" void kernel_launch(void* const* d_in, const int* in_sizes, int n_in,
                              void* d_out, int out_size, void* d_ws, size_t ws_size,
                              hipStream_t stream) {
  (void)in_sizes; (void)n_in; (void)out_size; (void)ws_size;
  const float* x  = (const float*)d_in[0];
  const float* W1 = (const float*)d_in[1];
  const float* b1 = (const float*)d_in[2];
  const float* W2 = (const float*)d_in[3];
  const float* b2 = (const float*)d_in[4];
  const float* W3 = (const float*)d_in[5];
  const float* b3 = (const float*)d_in[6];
  const float* W4 = (const float*)d_in[7];
  const float* b4 = (const float*)d_in[8];
  float* ws = (float*)d_ws;

  codec_kernel<<<NPLANES, 512, 0, stream>>>(x, W1, b1, W2, b2, W3, b3, W4, b4, ws);
  finalize_kernel<<<1, 64, 0, stream>>>(ws, (float*)d_out);
}

// Round 6
// 4654.182 us; speedup vs baseline: 3.7578x; 1.2291x over previous
//
#include <hip/hip_runtime.h>

#define NPLANES 24
#define IMG 192
#define RING_W 193   // f32 delta ring, stride 193 dwords (odd -> conflict-free)
#define TSTEPS 926   // wavefront t = 4*i + j

typedef _Float16 h2 __attribute__((ext_vector_type(2)));
typedef __fp16   fp16x2 __attribute__((ext_vector_type(2)));

__device__ __forceinline__ h2 asH2(float f) { union { float f; h2 h; } u; u.f = f; return u.h; }

__device__ __forceinline__ float fdot2(h2 a, h2 b, float c) {
#if __has_builtin(__builtin_amdgcn_fdot2)
  return __builtin_amdgcn_fdot2(a, b, c, false);
#else
  return c + (float)a.x * (float)b.x + (float)a.y * (float)b.y;
#endif
}

__device__ __forceinline__ h2 pk(float a, float b) {
  union { fp16x2 p; h2 h; } u;
  u.p = __builtin_amdgcn_cvt_pkrtz(a, b);   // v_cvt_pkrtz_f16_f32
  return u.h;
}

__device__ __forceinline__ float fast_tanh(float x) {
  float e = __expf(2.0f * x);
  return 1.0f - 2.0f / (e + 1.0f);
}

// One block per (b,c) plane, 512 threads = 8 waves.
// lane L <-> interior row i == L (mod 64); x-window in registers (slides);
// delta taps per-lane from f32 LDS ring. Weights + activations in f16,
// fp32 accumulation via v_dot2_f32_f16.
// Phases: A: L1 (12 n/wave, 8 waves) | B: L2 (3 n/wave, 8 waves)
//         | C: L3 (3 n/wave, waves 0-3 ONLY -> exactly 12 neurons) + L4 partial
//         | D: wave 0 sums 4 partials, delta, ring write.
__launch_bounds__(512)
__global__ void codec_kernel(const float* __restrict__ x,
                             const float* __restrict__ W1g, const float* __restrict__ b1g,
                             const float* __restrict__ W2g, const float* __restrict__ b2g,
                             const float* __restrict__ W3g, const float* __restrict__ b3g,
                             const float* __restrict__ W4g, const float* __restrict__ b4g,
                             float* __restrict__ ws)
{
  __shared__ float     ringL[64 * RING_W];   // 49408 B (f32; cols 0..2,189..191 stay 0)
  __shared__ _Float16  h1L[64 * 104];        // 13312 B, stride 104 halfs = 13*16B
  __shared__ _Float16  h2L[64 * 40];         //  5120 B, stride 40 halfs = 5*16B
  __shared__ float     p4L[64 * 9];          //  2304 B
  __shared__ _Float16  w1H[96 * 48];         //  9216 B neuron-major
  __shared__ _Float16  w2H[24 * 96];         //  4608 B
  __shared__ _Float16  w3H[12 * 24];         //   576 B
  __shared__ float     w4F[12];
  __shared__ float     b1L[96], b2L[24], b3L[12], b4L[1];
  // ~85 KB LDS

  const int tid  = threadIdx.x;
  const int lane = tid & 63;
  const int w = __builtin_amdgcn_readfirstlane(tid >> 6);
  const float* __restrict__ xp = x + (size_t)blockIdx.x * (IMG * IMG);

  for (int u = tid; u < 64 * RING_W; u += 512) ringL[u] = 0.0f;
  for (int u = tid; u < 96 * 48; u += 512) { int n = u / 48, k = u - n * 48; w1H[u] = (_Float16)W1g[k * 96 + n]; }
  for (int u = tid; u < 24 * 96; u += 512) { int n = u / 96, k = u - n * 96; w2H[u] = (_Float16)W2g[k * 24 + n]; }
  for (int u = tid; u < 12 * 24; u += 512) { int n = u / 24, k = u - n * 24; w3H[u] = (_Float16)W3g[k * 12 + n]; }
  if (tid < 12) w4F[tid] = W4g[tid];
  if (tid < 96) b1L[tid] = b1g[tid];
  if (tid < 24) b2L[tid] = b2g[tid];
  if (tid < 12) b3L[tid] = b3g[tid];
  if (tid == 0) b4L[0] = b4g[0];
  __syncthreads();

  float xw[3][7], xl[3], xt = 0.0f;   // per-lane sliding x-window (f32)
  float sumsq = 0.0f;

  for (int t = 0; t < TSTEPS; ++t) {
    const int i_min = (t <= 185) ? 0 : ((t - 182) >> 2);
    const int i_max = (t >> 2) > 185 ? 185 : (t >> 2);
    const int k64 = (i_min - lane + 63) >> 6;
    const int i = lane + (k64 << 6);
    const bool active = (i <= i_max);
    const int j = t - 4 * i;

    // ---- phase A: slide window, read taps, pack f16 features, L1 ----
    if (active) {
      const float* xrow = xp + i * IMG + j;
      if (j == 0) {
        #pragma unroll
        for (int r = 0; r < 3; ++r)
          #pragma unroll
          for (int c = 0; c < 7; ++c) xw[r][c] = xrow[r * IMG + c];
        #pragma unroll
        for (int c = 0; c < 3; ++c) xl[c] = xrow[3 * IMG + c];
        xt = xrow[3 * IMG + 3];
      } else {
        #pragma unroll
        for (int r = 0; r < 3; ++r) {
          #pragma unroll
          for (int c = 0; c < 6; ++c) xw[r][c] = xw[r][c + 1];
          xw[r][6] = xrow[r * IMG + 6];
        }
        xl[0] = xl[1]; xl[1] = xl[2]; xl[2] = xt;
        xt = xrow[3 * IMG + 3];
      }

      float d24[24];
      const int base0 = ((i - 3) & 63) * RING_W + j;
      const int base1 = ((i - 2) & 63) * RING_W + j;
      const int base2 = ((i - 1) & 63) * RING_W + j;
      const int base3 = (i & 63) * RING_W + j;
      #pragma unroll
      for (int d = 0; d < 7; ++d) d24[d]      = ringL[base0 + d];
      #pragma unroll
      for (int d = 0; d < 7; ++d) d24[7 + d]  = ringL[base1 + d];
      #pragma unroll
      for (int d = 0; d < 7; ++d) d24[14 + d] = ringL[base2 + d];
      #pragma unroll
      for (int d = 0; d < 3; ++d) d24[21 + d] = ringL[base3 + d];

      float fx[24];
      #pragma unroll
      for (int r = 0; r < 3; ++r)
        #pragma unroll
        for (int c = 0; c < 7; ++c) fx[7 * r + c] = xw[r][c];
      fx[21] = xl[0]; fx[22] = xl[1]; fx[23] = xl[2];

      h2 fr2[24];
      #pragma unroll
      for (int p = 0; p < 12; ++p) fr2[p]      = pk(fx[2 * p], fx[2 * p + 1]);
      #pragma unroll
      for (int p = 0; p < 12; ++p) fr2[12 + p] = pk(d24[2 * p], d24[2 * p + 1]);

      // L1: 12 neurons, 6 b128 weight-broadcast chunks each
      float o2[6];
      #pragma unroll
      for (int mm = 0; mm < 6; ++mm) {
        float t01[2];
        #pragma unroll
        for (int m2 = 0; m2 < 2; ++m2) {
          const int n = w * 12 + mm * 2 + m2;
          const _Float16* wr = &w1H[n * 48];
          float a = b1L[n];
          #pragma unroll
          for (int q = 0; q < 6; ++q) {
            float4 wv = *(const float4*)&wr[8 * q];     // wave-uniform broadcast
            a = fdot2(fr2[4*q+0], asH2(wv.x), a);
            a = fdot2(fr2[4*q+1], asH2(wv.y), a);
            a = fdot2(fr2[4*q+2], asH2(wv.z), a);
            a = fdot2(fr2[4*q+3], asH2(wv.w), a);
          }
          t01[m2] = fast_tanh(a);
        }
        union { h2 h; float f; } u; u.h = pk(t01[0], t01[1]);
        o2[mm] = u.f;
      }
      #pragma unroll
      for (int q = 0; q < 3; ++q)
        *(float2*)&h1L[lane * 104 + w * 12 + 4 * q] = make_float2(o2[2*q], o2[2*q+1]);
    }
    __syncthreads();

    // ---- phase B: L2, 3 neurons / wave, h1 streamed once ----
    if (active) {
      const int n0 = w * 3;
      const _Float16* wr0 = &w2H[(n0 + 0) * 96];
      const _Float16* wr1 = &w2H[(n0 + 1) * 96];
      const _Float16* wr2 = &w2H[(n0 + 2) * 96];
      float a0 = b2L[n0], a1 = b2L[n0 + 1], a2 = b2L[n0 + 2];
      #pragma unroll
      for (int q = 0; q < 12; ++q) {
        float4 hv = *(const float4*)&h1L[lane * 104 + 8 * q];   // per-lane, stride 13*16B
        float4 u0 = *(const float4*)&wr0[8 * q];
        float4 u1 = *(const float4*)&wr1[8 * q];
        float4 u2 = *(const float4*)&wr2[8 * q];
        h2 hx = asH2(hv.x), hy = asH2(hv.y), hz = asH2(hv.z), hw = asH2(hv.w);
        a0 = fdot2(hx, asH2(u0.x), a0); a0 = fdot2(hy, asH2(u0.y), a0);
        a0 = fdot2(hz, asH2(u0.z), a0); a0 = fdot2(hw, asH2(u0.w), a0);
        a1 = fdot2(hx, asH2(u1.x), a1); a1 = fdot2(hy, asH2(u1.y), a1);
        a1 = fdot2(hz, asH2(u1.z), a1); a1 = fdot2(hw, asH2(u1.w), a1);
        a2 = fdot2(hx, asH2(u2.x), a2); a2 = fdot2(hy, asH2(u2.y), a2);
        a2 = fdot2(hz, asH2(u2.z), a2); a2 = fdot2(hw, asH2(u2.w), a2);
      }
      h2L[lane * 40 + n0 + 0] = (_Float16)fast_tanh(a0);
      h2L[lane * 40 + n0 + 1] = (_Float16)fast_tanh(a1);
      h2L[lane * 40 + n0 + 2] = (_Float16)fast_tanh(a2);
    }
    __syncthreads();

    // ---- phase C: L3, waves 0..3 ONLY, 3 neurons each (n = 0..11) + L4 partial ----
    if (w < 4) {
      if (active) {
        h2 g2[12];
        #pragma unroll
        for (int q = 0; q < 3; ++q) {
          float4 gv = *(const float4*)&h2L[lane * 40 + 8 * q];
          g2[4*q+0] = asH2(gv.x); g2[4*q+1] = asH2(gv.y);
          g2[4*q+2] = asH2(gv.z); g2[4*q+3] = asH2(gv.w);
        }
        float p = 0.0f;
        #pragma unroll
        for (int m = 0; m < 3; ++m) {
          const int n = w * 3 + m;
          const _Float16* wr = &w3H[n * 24];
          float a = b3L[n];
          #pragma unroll
          for (int q = 0; q < 3; ++q) {
            float4 wv = *(const float4*)&wr[8 * q];
            a = fdot2(g2[4*q+0], asH2(wv.x), a);
            a = fdot2(g2[4*q+1], asH2(wv.y), a);
            a = fdot2(g2[4*q+2], asH2(wv.z), a);
            a = fdot2(g2[4*q+3], asH2(wv.w), a);
          }
          p = fmaf(fast_tanh(a), w4F[n], p);
        }
        p4L[lane * 9 + w] = p;
      }
    }
    __syncthreads();

    // ---- phase D: wave 0 sums 4 partials, finishes L4, writes delta ----
    if (w == 0) {
      if (active) {
        float s = b4L[0];
        #pragma unroll
        for (int q = 0; q < 4; ++q) s += p4L[lane * 9 + q];
        float pred = fast_tanh(s);
        float d = xt - pred;
        ringL[(i & 63) * RING_W + j + 3] = d;
        sumsq += d * d;
      }
    }
    __syncthreads();
  }

  if (w == 0) {
    #pragma unroll
    for (int off = 32; off >= 1; off >>= 1)
      sumsq += __shfl_down(sumsq, off);
    if (lane == 0) ws[blockIdx.x] = sumsq;
  }
}

__global__ void finalize_kernel(const float* __restrict__ ws, float* __restrict__ out) {
  if (threadIdx.x == 0) {
    float s = 0.0f;
    #pragma unroll
    for (int p = 0; p < NPLANES; ++p) s += ws[p];
    out[0] = sqrtf(s / 875520.0f);   // b*c*(h-2)*w = 8*3*190*192
  }
}

extern "C" void kernel_launch(void* const* d_in, const int* in_sizes, int n_in,
                              void* d_out, int out_size, void* d_ws, size_t ws_size,
                              hipStream_t stream) {
  (void)in_sizes; (void)n_in; (void)out_size; (void)ws_size;
  const float* x  = (const float*)d_in[0];
  const float* W1 = (const float*)d_in[1];
  const float* b1 = (const float*)d_in[2];
  const float* W2 = (const float*)d_in[3];
  const float* b2 = (const float*)d_in[4];
  const float* W3 = (const float*)d_in[5];
  const float* b3 = (const float*)d_in[6];
  const float* W4 = (const float*)d_in[7];
  const float* b4 = (const float*)d_in[8];
  float* ws = (float*)d_ws;

  codec_kernel<<<NPLANES, 512, 0, stream>>>(x, W1, b1, W2, b2, W3, b3, W4, b4, ws);
  finalize_kernel<<<1, 64, 0, stream>>>(ws, (float*)d_out);
}

// Round 7
// 2543.517 us; speedup vs baseline: 6.8762x; 1.8298x over previous
//
#include <hip/hip_runtime.h>

#define NPLANES 24
#define IMG 192
#define RING_W 193   // f32 delta ring, 64 rows, stride 193 dwords (odd -> conflict-free)
#define TSTEPS 926   // wavefront t = 4*i + j

typedef _Float16 h2v   __attribute__((ext_vector_type(2)));
typedef _Float16 f16x8 __attribute__((ext_vector_type(8)));
typedef float    f32x4 __attribute__((ext_vector_type(4)));
typedef __fp16   fp16x2 __attribute__((ext_vector_type(2)));

__device__ __forceinline__ h2v asH2(float f) { union { float f; h2v h; } u; u.f = f; return u.h; }

__device__ __forceinline__ float fdot2(h2v a, h2v b, float c) {
  return __builtin_amdgcn_fdot2(a, b, c, false);
}

__device__ __forceinline__ h2v pk(float a, float b) {
  union { fp16x2 p; h2v h; } u;
  u.p = __builtin_amdgcn_cvt_pkrtz(a, b);
  return u.h;
}

__device__ __forceinline__ float fast_tanh(float x) {
  float e = __expf(2.0f * x);
  return 1.0f - 2.0f / (e + 1.0f);
}

// One block per (b,c) plane, 512 threads = 8 waves.
// Cell slot c = row i mod 48 (unique: window width <= 47 < 48). Per step:
//   W  (wave 7): finalize step t-1 (sum L3 partials, tanh, delta -> ring, sumsq)
//                then build step-t features (reg sliding x-window + ring taps)
//                into featA[48 cells][48 f16] (+16 zero-pad K->64).
//   L1 (waves 0-5): MFMA 16x16x32_f16, M=48 (3 m-tiles), N=96 (wave w = n-tile w),
//                K=64: 6 MFMA/wave. B1-frags persistent in VGPRs (ZERO in-loop
//                weight reads). D: col=lane&15 (neuron), row=quad*4+reg (cell).
//   L2 (waves 0-5): M=48, N=32 (24 real), K=96: wave w -> tile (m=w%3, nt=w/3),
//                3 MFMA/wave, B2-frags persistent.
//   L3 (waves 6,7): lane=cell, 6 L3 neurons each via fdot2, L4 partial -> p4L.
// 4 barriers/step. In-loop LDS traffic ~240 instrs (vs ~1250 in R6).
__launch_bounds__(512)
__global__ void codec_kernel(const float* __restrict__ x,
                             const float* __restrict__ W1g, const float* __restrict__ b1g,
                             const float* __restrict__ W2g, const float* __restrict__ b2g,
                             const float* __restrict__ W3g, const float* __restrict__ b3g,
                             const float* __restrict__ W4g, const float* __restrict__ b4g,
                             float* __restrict__ ws)
{
  __shared__ float     ringL[64 * RING_W];  // 49408 B
  __shared__ _Float16  featA[48 * 72];      //  6912 B: [cell][48 feat + 16 zero + 8 pad]
  __shared__ _Float16  h1A[48 * 104];       //  9984 B: [cell][96 + 8 pad]
  __shared__ _Float16  h2A[48 * 40];        //  3840 B: [cell][24 + 16 pad]
  __shared__ _Float16  w1B[96 * 72];        // 13824 B: [n][48 k + 16 zero + 8 pad]
  __shared__ _Float16  w2B[32 * 104];       //  6656 B: [n(24 real+8 zero)][96 + 8 pad]
  __shared__ _Float16  w3H[12 * 24];        //   576 B: [n][24]
  __shared__ float     p4L[48 * 2];         //   384 B
  __shared__ float     b1L[96], b2L[24], b3L[12], w4F[12], b4L[1];
  // ~92 KB LDS

  const int tid  = threadIdx.x;
  const int lane = tid & 63;
  const int w    = __builtin_amdgcn_readfirstlane(tid >> 6);
  const int lam  = lane & 15;
  const int quad = lane >> 4;
  const float* __restrict__ xp = x + (size_t)blockIdx.x * (IMG * IMG);

  // ---- one-time init ----
  for (int u = tid; u < 64 * RING_W; u += 512) ringL[u] = 0.0f;
  for (int u = tid; u < 48 * 72;  u += 512) featA[u] = (_Float16)0.f;
  for (int u = tid; u < 48 * 104; u += 512) h1A[u]   = (_Float16)0.f;
  for (int u = tid; u < 48 * 40;  u += 512) h2A[u]   = (_Float16)0.f;
  for (int u = tid; u < 96 * 72;  u += 512) {
    int n = u / 72, k = u - n * 72;
    w1B[u] = (k < 48) ? (_Float16)W1g[k * 96 + n] : (_Float16)0.f;
  }
  for (int u = tid; u < 32 * 104; u += 512) {
    int n = u / 104, k = u - n * 104;
    w2B[u] = (n < 24 && k < 96) ? (_Float16)W2g[k * 24 + n] : (_Float16)0.f;
  }
  for (int u = tid; u < 12 * 24; u += 512) { int n = u / 24, k = u - n * 24; w3H[u] = (_Float16)W3g[k * 12 + n]; }
  if (tid < 96) b1L[tid] = b1g[tid];
  if (tid < 24) b2L[tid] = b2g[tid];
  if (tid < 12) b3L[tid] = b3g[tid];
  if (tid < 12) w4F[tid] = W4g[tid];
  if (tid == 0) b4L[0] = b4g[0];
  __syncthreads();

  // ---- persistent B-fragments (weights in VGPRs, loaded ONCE) ----
  f16x8 B1[2] = {};
  f16x8 B2[3] = {};
  float bias1 = 0.f, bias2 = 0.f;
  int m2 = 0, n2 = 0;
  if (w < 6) {
    const int n1 = 16 * w + lam;
    B1[0] = *(const f16x8*)&w1B[n1 * 72 + quad * 8];
    B1[1] = *(const f16x8*)&w1B[n1 * 72 + quad * 8 + 32];
    bias1 = b1L[n1];
    m2 = w % 3;
    const int nt = w / 3;
    n2 = 16 * nt + lam;
    #pragma unroll
    for (int kt = 0; kt < 3; ++kt)
      B2[kt] = *(const f16x8*)&w2B[n2 * 104 + quad * 8 + 32 * kt];
    bias2 = (n2 < 24) ? b2L[n2] : 0.f;
  }

  float xw[3][7], xl[3], xt = 0.0f;   // wave-7 per-lane sliding x-window
  float sumsq = 0.0f;

  for (int t = 0; t <= TSTEPS; ++t) {
    // ======== Phase W: wave 7 — finalize (t-1), then build features for t ========
    if (w == 7 && lane < 48) {
      if (t > 0) {
        const int tp = t - 1;
        const int ipmin = (tp <= 185) ? 0 : ((tp - 182) >> 2);
        const int ipmax = (tp >> 2) > 185 ? 185 : (tp >> 2);
        const int kp = (ipmin - lane + 47) / 48;
        const int ip = lane + 48 * kp;
        if (ip <= ipmax) {
          const float s = b4L[0] + p4L[lane * 2 + 0] + p4L[lane * 2 + 1];
          const float pred = fast_tanh(s);
          const float d = xt - pred;                 // xt is from build(t-1)
          const int jp = tp - 4 * ip;
          ringL[(ip & 63) * RING_W + 3 + jp] = d;    // must precede tap reads below
          sumsq += d * d;
        }
      }
      if (t < TSTEPS) {
        const int i_min = (t <= 185) ? 0 : ((t - 182) >> 2);
        const int i_max = (t >> 2) > 185 ? 185 : (t >> 2);
        const int k48 = (i_min - lane + 47) / 48;
        const int i = lane + 48 * k48;
        if (i <= i_max) {
          const int j = t - 4 * i;
          const float* xrow = xp + i * IMG + j;
          if (j == 0) {                              // new row: cold-load window
            #pragma unroll
            for (int r = 0; r < 3; ++r)
              #pragma unroll
              for (int c = 0; c < 7; ++c) xw[r][c] = xrow[r * IMG + c];
            #pragma unroll
            for (int c = 0; c < 3; ++c) xl[c] = xrow[3 * IMG + c];
            xt = xrow[3 * IMG + 3];
          } else {                                   // slide right by one
            #pragma unroll
            for (int r = 0; r < 3; ++r) {
              #pragma unroll
              for (int c = 0; c < 6; ++c) xw[r][c] = xw[r][c + 1];
              xw[r][6] = xrow[r * IMG + 6];
            }
            xl[0] = xl[1]; xl[1] = xl[2]; xl[2] = xt;
            xt = xrow[3 * IMG + 3];
          }
          float d24[24];
          const int base0 = ((i - 3) & 63) * RING_W + j;
          const int base1 = ((i - 2) & 63) * RING_W + j;
          const int base2 = ((i - 1) & 63) * RING_W + j;
          const int base3 = (i & 63) * RING_W + j;
          #pragma unroll
          for (int d = 0; d < 7; ++d) d24[d]      = ringL[base0 + d];
          #pragma unroll
          for (int d = 0; d < 7; ++d) d24[7 + d]  = ringL[base1 + d];
          #pragma unroll
          for (int d = 0; d < 7; ++d) d24[14 + d] = ringL[base2 + d];
          #pragma unroll
          for (int d = 0; d < 3; ++d) d24[21 + d] = ringL[base3 + d];

          float fx[24];
          #pragma unroll
          for (int r = 0; r < 3; ++r)
            #pragma unroll
            for (int c = 0; c < 7; ++c) fx[7 * r + c] = xw[r][c];
          fx[21] = xl[0]; fx[22] = xl[1]; fx[23] = xl[2];

          union { h2v p[24]; float4 v[6]; } fb;
          #pragma unroll
          for (int p = 0; p < 12; ++p) fb.p[p]      = pk(fx[2 * p], fx[2 * p + 1]);
          #pragma unroll
          for (int p = 0; p < 12; ++p) fb.p[12 + p] = pk(d24[2 * p], d24[2 * p + 1]);
          #pragma unroll
          for (int q = 0; q < 6; ++q)
            *(float4*)&featA[lane * 72 + 8 * q] = fb.v[q];
        }
      }
    }
    __syncthreads();
    if (t == TSTEPS) break;

    // ======== Phase L1: waves 0-5, MFMA 48x96, K=64 ========
    if (w < 6) {
      f32x4 acc0 = {bias1, bias1, bias1, bias1};
      f32x4 acc1 = acc0, acc2 = acc0;
      const f16x8 a00 = *(const f16x8*)&featA[(0 * 16 + lam) * 72 + quad * 8];
      const f16x8 a01 = *(const f16x8*)&featA[(0 * 16 + lam) * 72 + quad * 8 + 32];
      const f16x8 a10 = *(const f16x8*)&featA[(1 * 16 + lam) * 72 + quad * 8];
      const f16x8 a11 = *(const f16x8*)&featA[(1 * 16 + lam) * 72 + quad * 8 + 32];
      const f16x8 a20 = *(const f16x8*)&featA[(2 * 16 + lam) * 72 + quad * 8];
      const f16x8 a21 = *(const f16x8*)&featA[(2 * 16 + lam) * 72 + quad * 8 + 32];
      acc0 = __builtin_amdgcn_mfma_f32_16x16x32_f16(a00, B1[0], acc0, 0, 0, 0);
      acc1 = __builtin_amdgcn_mfma_f32_16x16x32_f16(a10, B1[0], acc1, 0, 0, 0);
      acc2 = __builtin_amdgcn_mfma_f32_16x16x32_f16(a20, B1[0], acc2, 0, 0, 0);
      acc0 = __builtin_amdgcn_mfma_f32_16x16x32_f16(a01, B1[1], acc0, 0, 0, 0);
      acc1 = __builtin_amdgcn_mfma_f32_16x16x32_f16(a11, B1[1], acc1, 0, 0, 0);
      acc2 = __builtin_amdgcn_mfma_f32_16x16x32_f16(a21, B1[1], acc2, 0, 0, 0);
      const int ncol = 16 * w + lam;
      #pragma unroll
      for (int r = 0; r < 4; ++r)
        h1A[(0 * 16 + quad * 4 + r) * 104 + ncol] = (_Float16)fast_tanh(acc0[r]);
      #pragma unroll
      for (int r = 0; r < 4; ++r)
        h1A[(1 * 16 + quad * 4 + r) * 104 + ncol] = (_Float16)fast_tanh(acc1[r]);
      #pragma unroll
      for (int r = 0; r < 4; ++r)
        h1A[(2 * 16 + quad * 4 + r) * 104 + ncol] = (_Float16)fast_tanh(acc2[r]);
    }
    __syncthreads();

    // ======== Phase L2: waves 0-5, tile (m=w%3, nt=w/3), K=96 ========
    if (w < 6) {
      f32x4 acc = {bias2, bias2, bias2, bias2};
      const f16x8 c0 = *(const f16x8*)&h1A[(m2 * 16 + lam) * 104 + quad * 8];
      const f16x8 c1 = *(const f16x8*)&h1A[(m2 * 16 + lam) * 104 + quad * 8 + 32];
      const f16x8 c2 = *(const f16x8*)&h1A[(m2 * 16 + lam) * 104 + quad * 8 + 64];
      acc = __builtin_amdgcn_mfma_f32_16x16x32_f16(c0, B2[0], acc, 0, 0, 0);
      acc = __builtin_amdgcn_mfma_f32_16x16x32_f16(c1, B2[1], acc, 0, 0, 0);
      acc = __builtin_amdgcn_mfma_f32_16x16x32_f16(c2, B2[2], acc, 0, 0, 0);
      if (n2 < 24) {
        #pragma unroll
        for (int r = 0; r < 4; ++r)
          h2A[(m2 * 16 + quad * 4 + r) * 40 + n2] = (_Float16)fast_tanh(acc[r]);
      }
    }
    __syncthreads();

    // ======== Phase L3: waves 6,7 — 6 L3 neurons each + L4 partial ========
    if (w >= 6 && lane < 48) {
      const int i_min = (t <= 185) ? 0 : ((t - 182) >> 2);
      const int i_max = (t >> 2) > 185 ? 185 : (t >> 2);
      const int k48 = (i_min - lane + 47) / 48;
      const int i = lane + 48 * k48;
      if (i <= i_max) {
        const float4 g0 = *(const float4*)&h2A[lane * 40 + 0];
        const float4 g1 = *(const float4*)&h2A[lane * 40 + 8];
        const float4 g2 = *(const float4*)&h2A[lane * 40 + 16];
        h2v gp[12];
        gp[0] = asH2(g0.x); gp[1] = asH2(g0.y); gp[2]  = asH2(g0.z); gp[3]  = asH2(g0.w);
        gp[4] = asH2(g1.x); gp[5] = asH2(g1.y); gp[6]  = asH2(g1.z); gp[7]  = asH2(g1.w);
        gp[8] = asH2(g2.x); gp[9] = asH2(g2.y); gp[10] = asH2(g2.z); gp[11] = asH2(g2.w);
        const int nb = (w - 6) * 6;
        float p = 0.0f;
        #pragma unroll
        for (int m = 0; m < 6; ++m) {
          const int n = nb + m;
          float a = b3L[n];
          const float4 wv0 = *(const float4*)&w3H[n * 24 + 0];
          const float4 wv1 = *(const float4*)&w3H[n * 24 + 8];
          const float4 wv2 = *(const float4*)&w3H[n * 24 + 16];
          a = fdot2(gp[0], asH2(wv0.x), a); a = fdot2(gp[1], asH2(wv0.y), a);
          a = fdot2(gp[2], asH2(wv0.z), a); a = fdot2(gp[3], asH2(wv0.w), a);
          a = fdot2(gp[4], asH2(wv1.x), a); a = fdot2(gp[5], asH2(wv1.y), a);
          a = fdot2(gp[6], asH2(wv1.z), a); a = fdot2(gp[7], asH2(wv1.w), a);
          a = fdot2(gp[8], asH2(wv2.x), a); a = fdot2(gp[9], asH2(wv2.y), a);
          a = fdot2(gp[10], asH2(wv2.z), a); a = fdot2(gp[11], asH2(wv2.w), a);
          p = fmaf(fast_tanh(a), w4F[n], p);
        }
        p4L[lane * 2 + (w - 6)] = p;
      }
    }
    __syncthreads();
  }

  // only wave 7 holds sumsq
  if (w == 7) {
    #pragma unroll
    for (int off = 32; off >= 1; off >>= 1)
      sumsq += __shfl_down(sumsq, off);
    if (lane == 0) ws[blockIdx.x] = sumsq;
  }
}

__global__ void finalize_kernel(const float* __restrict__ ws, float* __restrict__ out) {
  if (threadIdx.x == 0) {
    float s = 0.0f;
    #pragma unroll
    for (int p = 0; p < NPLANES; ++p) s += ws[p];
    out[0] = sqrtf(s / 875520.0f);   // b*c*(h-2)*w = 8*3*190*192
  }
}

extern "C" void kernel_launch(void* const* d_in, const int* in_sizes, int n_in,
                              void* d_out, int out_size, void* d_ws, size_t ws_size,
                              hipStream_t stream) {
  (void)in_sizes; (void)n_in; (void)out_size; (void)ws_size;
  const float* x  = (const float*)d_in[0];
  const float* W1 = (const float*)d_in[1];
  const float* b1 = (const float*)d_in[2];
  const float* W2 = (const float*)d_in[3];
  const float* b2 = (const float*)d_in[4];
  const float* W3 = (const float*)d_in[5];
  const float* b3 = (const float*)d_in[6];
  const float* W4 = (const float*)d_in[7];
  const float* b4 = (const float*)d_in[8];
  float* ws = (float*)d_ws;

  codec_kernel<<<NPLANES, 512, 0, stream>>>(x, W1, b1, W2, b2, W3, b3, W4, b4, ws);
  finalize_kernel<<<1, 64, 0, stream>>>(ws, (float*)d_out);
}